// Round 17
// baseline (550.000 us; speedup 1.0000x reference)
//
#include <hip/hip_runtime.h>

#define ZD 256    // Z_NH
#define NE 1000   // NUM_ENTRY
#define NP 1024   // padded entries

typedef __attribute__((ext_vector_type(8))) short short8;
typedef __attribute__((ext_vector_type(4))) float f32x4;

static __device__ __forceinline__ unsigned short f2bf(float x) {
    unsigned u = __float_as_uint(x);
    u = (u + 0x7FFFu + ((u >> 16) & 1u)) >> 16;
    return (unsigned short)u;
}
static __device__ __forceinline__ float bf2f(unsigned short u) {
    return __uint_as_float((unsigned)u << 16);
}

// ---------------------------------------------------------------------------
// prep_e: eh (bf16 swizzled, ws) + el (bf16 residual, swizzled, ws+512KB)
// + en exact pairwise. Same swizzle layout for both halves. (R13-validated)
// ---------------------------------------------------------------------------
__global__ __launch_bounds__(64) void prep_e(const float* __restrict__ emb,
                                             unsigned char* __restrict__ ebB,
                                             unsigned char* __restrict__ elB,
                                             float* __restrict__ en) {
    int e = blockIdx.x * 64 + threadIdx.x;
    if (e >= NP) return;
    unsigned base = (unsigned)e * 512u;
    unsigned x = ((unsigned)e & 7u) << 4;
    if (e < NE) {
        const float* row = emb + (size_t)e * ZD;
        for (int k = 0; k < ZD; k += 2) {  // 2k%4==0, pair stays in same dword
            unsigned off = (base + 2u * k) ^ x;
            unsigned short h0 = f2bf(row[k]);
            unsigned short h1 = f2bf(row[k + 1]);
            *(unsigned short*)(ebB + off)     = h0;
            *(unsigned short*)(ebB + off + 2) = h1;
            *(unsigned short*)(elB + off)     = f2bf(__fsub_rn(row[k],     bf2f(h0)));
            *(unsigned short*)(elB + off + 2) = f2bf(__fsub_rn(row[k + 1], bf2f(h1)));
        }
        float r[8];
        #pragma unroll
        for (int j = 0; j < 8; ++j) { float v = row[j]; r[j] = __fmul_rn(v, v); }
        for (int i = 8; i < 128; i += 8)
            #pragma unroll
            for (int j = 0; j < 8; ++j) { float v = row[i + j]; r[j] = __fadd_rn(r[j], __fmul_rn(v, v)); }
        float s1 = __fadd_rn(__fadd_rn(__fadd_rn(r[0], r[1]), __fadd_rn(r[2], r[3])),
                             __fadd_rn(__fadd_rn(r[4], r[5]), __fadd_rn(r[6], r[7])));
        #pragma unroll
        for (int j = 0; j < 8; ++j) { float v = row[128 + j]; r[j] = __fmul_rn(v, v); }
        for (int i = 136; i < 256; i += 8)
            #pragma unroll
            for (int j = 0; j < 8; ++j) { float v = row[i + j]; r[j] = __fadd_rn(r[j], __fmul_rn(v, v)); }
        float s2 = __fadd_rn(__fadd_rn(__fadd_rn(r[0], r[1]), __fadd_rn(r[2], r[3])),
                             __fadd_rn(__fadd_rn(r[4], r[5]), __fadd_rn(r[6], r[7])));
        en[e] = __fadd_rn(s1, s2);
    } else {
        for (int k = 0; k < 128; ++k) {
            *(unsigned*)(ebB + base + 4u * k) = 0u;
            *(unsigned*)(elB + base + 4u * k) = 0u;
        }
        en[e] = __builtin_inff();
    }
}

// ---------------------------------------------------------------------------
// prep_h: hb (bf16 rows, stored in out_q region, row stride 512 ushorts) and
// hn (exact numpy-pairwise, stored in out_i region as float bits) — R16 ver.
// ---------------------------------------------------------------------------
__global__ __launch_bounds__(256) void prep_h(const float* __restrict__ h,
                                              unsigned short* __restrict__ hb,
                                              float* __restrict__ hn) {
    __shared__ float L[64][257];
    const int t = threadIdx.x;
    const long row0 = (long)blockIdx.x * 64;
    const int kq = (t & 63) * 4;
    const int rq = t >> 6;
    #pragma unroll
    for (int p = 0; p < 16; ++p) {
        int row = p * 4 + rq;
        float4 v = *(const float4*)(h + (row0 + row) * ZD + kq);
        L[row][kq] = v.x; L[row][kq + 1] = v.y; L[row][kq + 2] = v.z; L[row][kq + 3] = v.w;
    }
    __syncthreads();
    #pragma unroll
    for (int p = 0; p < 16; ++p) {
        int row = p * 4 + rq;
        ushort4 o;
        o.x = f2bf(L[row][kq]);     o.y = f2bf(L[row][kq + 1]);
        o.z = f2bf(L[row][kq + 2]); o.w = f2bf(L[row][kq + 3]);
        *(ushort4*)(hb + (row0 + row) * 512 + kq) = o;
    }
    if (t < 64) {
        float r[8];
        #pragma unroll
        for (int j = 0; j < 8; ++j) { float v = L[t][j]; r[j] = __fmul_rn(v, v); }
        for (int i = 8; i < 128; i += 8)
            #pragma unroll
            for (int j = 0; j < 8; ++j) { float v = L[t][i + j]; r[j] = __fadd_rn(r[j], __fmul_rn(v, v)); }
        float s1 = __fadd_rn(__fadd_rn(__fadd_rn(r[0], r[1]), __fadd_rn(r[2], r[3])),
                             __fadd_rn(__fadd_rn(r[4], r[5]), __fadd_rn(r[6], r[7])));
        #pragma unroll
        for (int j = 0; j < 8; ++j) { float v = L[t][128 + j]; r[j] = __fmul_rn(v, v); }
        for (int i = 136; i < 256; i += 8)
            #pragma unroll
            for (int j = 0; j < 8; ++j) { float v = L[t][i + j]; r[j] = __fadd_rn(r[j], __fmul_rn(v, v)); }
        float s2 = __fadd_rn(__fadd_rn(__fadd_rn(r[0], r[1]), __fadd_rn(r[2], r[3])),
                             __fadd_rn(__fadd_rn(r[4], r[5]), __fadd_rn(r[6], r[7])));
        hn[row0 + t] = __fadd_rn(s1, s2);
    }
}

// ---------------------------------------------------------------------------
// K1 main: 2-term split-precision: dot ~= hh*eh + hh*el (B-side exact to
// 2^-18; only hh A-frags -> R16's exact register shape). tau = 7e-5*sqrt(hn)
// +2.5e-4 (R13-validated, absmax 0) -> verify set ~2.6x smaller.
// 16 x 32KB chunks (eh 32K + el 32K = 64.3 KB LDS -> 2 blocks/CU kept).
// #pragma unroll 1 on c and nt loops (R16 anti-spill lesson); kt body is
// two sequential copies of R16's proven fully-unrolled kt<4 loop.
// Marker epilogue: cnt==1 -> out_l[r]=besti; verify -> -(cnt) + record;
// exhaust -> -99.
// ---------------------------------------------------------------------------
__global__ __launch_bounds__(1024, 4) void vq_main(const unsigned char* __restrict__ ebB,
                                                   const unsigned char* __restrict__ elB,
                                                   const float* __restrict__ en,
                                                   float* out, int M) {
    extern __shared__ char lds[];
    char* BsEH = lds;                         // 32768 B eh chunk (swizzled)
    char* BsEL = lds + 32768;                 // 32768 B el chunk (swizzled)
    float* en_s = (float*)(lds + 65536);      // 64 floats

    const int t  = threadIdx.x;
    const int lane = t & 63;
    const int wv = t >> 6;                    // 0..15
    const int g  = lane >> 4;                 // 0..3
    const int lg = lane & 15;
    const long rbase = (long)blockIdx.x * 256 + wv * 16;

    const unsigned short* hb = (const unsigned short*)out;    // bf16 hh rows
    const float* hnp = out + (size_t)M * ZD;                  // hn values

    short8 afrag[8];
    {
        const unsigned short* hr = hb + (rbase + lg) * 512;
        #pragma unroll
        for (int kt = 0; kt < 8; ++kt)
            afrag[kt] = *(const short8*)(hr + kt * 32 + g * 8);
    }
    float hnr[4], taur[4];
    #pragma unroll
    for (int i = 0; i < 4; ++i) {
        hnr[i] = hnp[rbase + g * 4 + i];
        // 2-term split: Delta <= 3.1e-5*sqrt(hn) + ~1e-4; tau >= 2*Delta
        taur[i] = 7.0e-5f * sqrtf(hnr[i]) + 2.5e-4f;
    }

    const float INF = __builtin_inff();
    float bv0[4], bv1[4], bv2[4], bv3[4];
    int   bi0[4], bi1[4], bi2[4], bi3[4];
    #pragma unroll
    for (int i = 0; i < 4; ++i) {
        bv0[i] = INF; bv1[i] = INF; bv2[i] = INF; bv3[i] = INF;
        bi0[i] = 0;   bi1[i] = 0;   bi2[i] = 0;   bi3[i] = 0;
    }

    #pragma unroll 1
    for (int c = 0; c < 16; ++c) {
        { // stage eh and el 32KB chunks linearly (coalesced, conflict-free)
            const uint4* srcEH = (const uint4*)(ebB + (size_t)c * 32768);
            const uint4* srcEL = (const uint4*)(elB + (size_t)c * 32768);
            uint4* dstEH = (uint4*)BsEH;
            uint4* dstEL = (uint4*)BsEL;
            #pragma unroll
            for (int p = 0; p < 2; ++p) dstEH[p * 1024 + t] = srcEH[p * 1024 + t];
            #pragma unroll
            for (int p = 0; p < 2; ++p) dstEL[p * 1024 + t] = srcEL[p * 1024 + t];
        }
        if (t < 16) {
            float4 v = *(const float4*)(en + c * 64 + t * 4);
            *(float4*)(en_s + t * 4) = v;
        }
        __syncthreads();

        #pragma unroll 1
        for (int nt = 0; nt < 4; ++nt) {
            f32x4 a0 = {0.f, 0.f, 0.f, 0.f};   // hh*eh
            f32x4 a1 = {0.f, 0.f, 0.f, 0.f};   // hh*el
            const int nb = nt * 16 + lg;        // entry in chunk 0..63
            const unsigned x = ((unsigned)lg & 7u) << 4;
            const unsigned rowb = (unsigned)nb * 512u;
            #pragma unroll
            for (int kt = 0; kt < 4; ++kt) {
                short8 b0 = *(const short8*)(BsEH + ((rowb + (unsigned)kt * 64u + g * 16u) ^ x));
                short8 b1 = *(const short8*)(BsEH + ((rowb + (unsigned)(kt + 4) * 64u + g * 16u) ^ x));
                a0 = __builtin_amdgcn_mfma_f32_16x16x32_bf16(afrag[kt],     b0, a0, 0, 0, 0);
                a0 = __builtin_amdgcn_mfma_f32_16x16x32_bf16(afrag[kt + 4], b1, a0, 0, 0, 0);
            }
            #pragma unroll
            for (int kt = 0; kt < 4; ++kt) {
                short8 b0 = *(const short8*)(BsEL + ((rowb + (unsigned)kt * 64u + g * 16u) ^ x));
                short8 b1 = *(const short8*)(BsEL + ((rowb + (unsigned)(kt + 4) * 64u + g * 16u) ^ x));
                a1 = __builtin_amdgcn_mfma_f32_16x16x32_bf16(afrag[kt],     b0, a1, 0, 0, 0);
                a1 = __builtin_amdgcn_mfma_f32_16x16x32_bf16(afrag[kt + 4], b1, a1, 0, 0, 0);
            }
            const int eIdx = c * 64 + nb;
            const float ene = en_s[nb];
            #pragma unroll
            for (int i = 0; i < 4; ++i) {
                float dot = __fadd_rn(a0[i], a1[i]);
                float d = __fsub_rn(__fadd_rn(hnr[i], ene), __fmul_rn(2.0f, dot));
                if (__any(d < bv3[i])) {
                    bool l3 = d < bv3[i], l2 = d < bv2[i], l1 = d < bv1[i], l0 = d < bv0[i];
                    bv3[i] = l3 ? (l2 ? bv2[i] : d) : bv3[i];
                    bi3[i] = l3 ? (l2 ? bi2[i] : eIdx) : bi3[i];
                    bv2[i] = l2 ? (l1 ? bv1[i] : d) : bv2[i];
                    bi2[i] = l2 ? (l1 ? bi1[i] : eIdx) : bi2[i];
                    bv1[i] = l1 ? (l0 ? bv0[i] : d) : bv1[i];
                    bi1[i] = l1 ? (l0 ? bi0[i] : eIdx) : bi1[i];
                    bv0[i] = l0 ? d : bv0[i];
                    bi0[i] = l0 ? eIdx : bi0[i];
                }
            }
        }
        __syncthreads();
    }

    float* out_q = out;
    float* out_i = out + (size_t)M * ZD;
    float* out_l = out_i + M;

    #pragma unroll 1
    for (int i = 0; i < 4; ++i) {
        const long r = rbase + g * 4 + i;

        float gmin = bv0[i];
        #pragma unroll
        for (int o = 1; o < 16; o <<= 1) gmin = fminf(gmin, __shfl_xor(gmin, o, 64));
        const float thr = gmin + taur[i];

        unsigned b0 = (unsigned)(__ballot(bv0[i] <= thr) >> (g * 16)) & 0xFFFFu;
        unsigned b1 = (unsigned)(__ballot(bv1[i] <= thr) >> (g * 16)) & 0xFFFFu;
        unsigned b2 = (unsigned)(__ballot(bv2[i] <= thr) >> (g * 16)) & 0xFFFFu;
        unsigned b3 = (unsigned)(__ballot(bv3[i] <= thr) >> (g * 16)) & 0xFFFFu;
        const int cnt = __popc(b0) + __popc(b1) + __popc(b2) + __popc(b3);
        const bool ex = (b3 != 0u) || (cnt > 7);

        if (cnt == 1 && !ex) {
            // single in-window candidate: provably the argmin (tau > 2*Delta)
            if (bv0[i] <= thr) out_l[r] = (float)bi0[i];
        } else if (!ex) {
            float* rec = out_q + (size_t)r * ZD;
            if (lg == 0) {
                rec[0] = (float)cnt;
                out_l[r] = -(float)cnt;          // verify marker
            }
            const unsigned mlt = (1u << lg) - 1u;
            int base = 1;
            if (bv0[i] <= thr) rec[base + __popc(b0 & mlt)] = (float)bi0[i];
            base += __popc(b0);
            if (bv1[i] <= thr) rec[base + __popc(b1 & mlt)] = (float)bi1[i];
            base += __popc(b1);
            if (bv2[i] <= thr) rec[base + __popc(b2 & mlt)] = (float)bi2[i];
        } else {
            if (lg == 0) out_l[r] = -99.0f;      // exhaustive marker
        }
    }
}

// ---------------------------------------------------------------------------
// K2 merged finalize+stream (R14/R16 verbatim): 8192 blocks x 256 thr, 16
// rows/block (4/wave). Verify rows resolved with R10's proven wave-level
// body (coalesced 1KB stages into the wave's LDS slice, one bit-exact chain
// per lane, lex (d,idx) reduce), latency hidden under 32K waves of stream
// BW. Then R1's byte-exact epilogue.
// ---------------------------------------------------------------------------
__global__ __launch_bounds__(256) void vq_fs(const float* __restrict__ h,
                                             const float* __restrict__ emb,
                                             const float* __restrict__ en,
                                             float* __restrict__ out, int M) {
    extern __shared__ float Lall[];          // 4 waves x 8 rows x 260 floats
    const int t    = threadIdx.x;
    const int wv   = t >> 6;      // 0..3
    const int lane = t & 63;
    const int g    = lane >> 4;   // 0..3
    const int lg   = lane & 15;
    float* Lw = Lall + wv * (8 * 260);

    float* out_q = out;
    float* out_i = out + (size_t)M * ZD;
    float* out_l = out_i + M;
    const float INF = __builtin_inff();

    const long r = (long)blockIdx.x * 16 + wv * 4 + g;   // this group's row
    const float mk = out_l[r];                            // marker/besti
    int besti = (mk >= 0.f) ? (int)mk : 0;

    // ---- wave-level: resolve rows needing verification, one at a time ----
    unsigned long long vb = __ballot(mk < 0.f);
    #pragma unroll 1
    for (int gx = 0; gx < 4; ++gx) {
        if (!((vb >> (gx * 16)) & 1ull)) continue;
        const long rx = (long)blockIdx.x * 16 + wv * 4 + gx;
        const float mx = __shfl(mk, gx * 16, 64);
        const float hnx = out_i[rx];

        asm volatile("s_waitcnt lgkmcnt(0)" ::: "memory");  // WAR vs prev row

        int bix;
        if (mx > -50.f) {
            const int cnt = -(int)mx;                       // 2..7
            const float* rec = out_q + (size_t)rx * ZD;
            const float4 rA = *(const float4*)(rec);        // cnt,i0,i1,i2
            const float4 rB = *(const float4*)(rec + 4);    // i3,i4,i5,i6

            { // stage h row (coalesced 1KB, whole wave)
                float4 v = *(const float4*)(h + (size_t)rx * ZD + lane * 4);
                *(float4*)(Lw + lane * 4) = v;
            }
            #pragma unroll 1
            for (int q = 0; q < cnt; ++q) {   // stage candidate e rows
                const float fq = (q == 0) ? rA.y : (q == 1) ? rA.z : (q == 2) ? rA.w
                               : (q == 3) ? rB.x : (q == 4) ? rB.y : (q == 5) ? rB.z : rB.w;
                const int eidx = (int)fq;
                float4 v = *(const float4*)(emb + (size_t)eidx * ZD + lane * 4);
                *(float4*)(Lw + (1 + q) * 260 + lane * 4) = v;
            }
            asm volatile("s_waitcnt lgkmcnt(0)" ::: "memory");  // RAW

            float bd = INF;
            int   bi = 0x7FFFFFFF;
            if (lane < cnt) {
                const float fq = (lane == 0) ? rA.y : (lane == 1) ? rA.z : (lane == 2) ? rA.w
                               : (lane == 3) ? rB.x : (lane == 4) ? rB.y : (lane == 5) ? rB.z : rB.w;
                const int idx = (int)fq;
                const float* hl = Lw;
                const float* el = Lw + (1 + lane) * 260;
                float dot = 0.f;
                #pragma unroll 8
                for (int k = 0; k < ZD; k += 4) {
                    dot = fmaf(hl[k],     el[k],     dot);
                    dot = fmaf(hl[k + 1], el[k + 1], dot);
                    dot = fmaf(hl[k + 2], el[k + 2], dot);
                    dot = fmaf(hl[k + 3], el[k + 3], dot);
                }
                bd = __fsub_rn(__fadd_rn(hnx, en[idx]), __fmul_rn(2.0f, dot));
                bi = idx;
            }
            #pragma unroll
            for (int o = 1; o < 8; o <<= 1) {  // lex (d,idx) min, lanes 0..7
                float ov = __shfl_xor(bd, o, 8);
                int   oi = __shfl_xor(bi, o, 8);
                if (ov < bd || (ov == bd && oi < bi)) { bd = ov; bi = oi; }
            }
            bix = __shfl(bi, 0, 64);
        } else {
            // exhaustive (ultra-rare): h from LDS, lane-parallel over entries
            {
                float4 v = *(const float4*)(h + (size_t)rx * ZD + lane * 4);
                *(float4*)(Lw + lane * 4) = v;
            }
            asm volatile("s_waitcnt lgkmcnt(0)" ::: "memory");
            float bd = INF;
            int   bi = 0x7FFFFFFF;
            for (int e = lane; e < NE; e += 64) {
                const float* er = emb + (size_t)e * ZD;
                float dot = 0.f;
                #pragma unroll 8
                for (int k = 0; k < ZD; k += 4) {
                    float4 ev = *(const float4*)(er + k);
                    dot = fmaf(Lw[k],     ev.x, dot);
                    dot = fmaf(Lw[k + 1], ev.y, dot);
                    dot = fmaf(Lw[k + 2], ev.z, dot);
                    dot = fmaf(Lw[k + 3], ev.w, dot);
                }
                float dx = __fsub_rn(__fadd_rn(hnx, en[e]), __fmul_rn(2.0f, dot));
                if (dx < bd || (dx == bd && e < bi)) { bd = dx; bi = e; }
            }
            #pragma unroll
            for (int o = 1; o < 64; o <<= 1) {
                float ov = __shfl_xor(bd, o, 64);
                int   oi = __shfl_xor(bi, o, 64);
                if (ov < bd || (ov == bd && oi < bi)) { bd = ov; bi = oi; }
            }
            bix = __shfl(bi, 0, 64);
        }
        if (g == gx) besti = bix;
    }

    // ---- stream: R1's byte-exact epilogue for this group's row ----
    const float* hrow = h + (size_t)r * ZD;
    const float* erow = emb + (size_t)besti * ZD;
    float csum = 0.0f;
    #pragma unroll
    for (int q4 = 0; q4 < 4; ++q4) {
        int k = lg * 16 + q4 * 4;
        float4 hv = *(const float4*)(hrow + k);
        float4 ev = *(const float4*)(erow + k);
        float dx = __fsub_rn(ev.x, hv.x);
        float dy = __fsub_rn(ev.y, hv.y);
        float dz = __fsub_rn(ev.z, hv.z);
        float dw = __fsub_rn(ev.w, hv.w);
        float4 o;
        o.x = __fadd_rn(hv.x, dx);
        o.y = __fadd_rn(hv.y, dy);
        o.z = __fadd_rn(hv.z, dz);
        o.w = __fadd_rn(hv.w, dw);
        *(float4*)(out_q + (size_t)r * ZD + k) = o;
        csum = fmaf(dx, dx, csum);
        csum = fmaf(dy, dy, csum);
        csum = fmaf(dz, dz, csum);
        csum = fmaf(dw, dw, csum);
    }
    #pragma unroll
    for (int o2 = 1; o2 < 16; o2 <<= 1) csum += __shfl_xor(csum, o2, 64);
    if (lg == 0) {
        float cmean = csum * (1.0f / 256.0f);
        out_i[r] = (float)besti;
        out_l[r] = __fadd_rn(__fmul_rn(cmean, 0.1f), __fmul_rn(cmean, 0.2f));
    }
}

extern "C" void kernel_launch(void* const* d_in, const int* in_sizes, int n_in,
                              void* d_out, int out_size, void* d_ws, size_t ws_size,
                              hipStream_t stream) {
    const float* h   = (const float*)d_in[0];
    const float* emb = (const float*)d_in[1];
    const int M = in_sizes[0] / ZD;   // 131072

    unsigned char* ebB = (unsigned char*)d_ws;               // 512 KB eh swizzled
    unsigned char* elB = ebB + (size_t)NP * ZD * 2;          // 512 KB el swizzled
    float* en = (float*)(elB + (size_t)NP * ZD * 2);         // 4 KB

    float* out = (float*)d_out;
    unsigned short* hb = (unsigned short*)d_out;             // bf16 hh rows
    float* hn = out + (size_t)M * ZD;                        // hn in out_i region

    prep_e<<<NP / 64, 64, 0, stream>>>(emb, ebB, elB, en);
    prep_h<<<M / 64, 256, 0, stream>>>(h, hb, hn);

    const size_t lds_bytes = 65536 + 256 + 16;               // 64.3 KB -> 2 blocks/CU
    (void)hipFuncSetAttribute((const void*)vq_main,
                              hipFuncAttributeMaxDynamicSharedMemorySize,
                              (int)lds_bytes);
    vq_main<<<M / 256, 1024, lds_bytes, stream>>>(ebB, elB, en, out, M);

    const size_t fs_lds = 4 * 8 * 260 * sizeof(float);       // 33280 B
    vq_fs<<<M / 16, 256, fs_lds, stream>>>(h, emb, en, out, M);
}

// Round 18
// 523.365 us; speedup vs baseline: 1.0509x; 1.0509x over previous
//
#include <hip/hip_runtime.h>

#define ZD 256    // Z_NH
#define NE 1000   // NUM_ENTRY
#define NP 1024   // padded entries

typedef __attribute__((ext_vector_type(8))) short short8;
typedef __attribute__((ext_vector_type(4))) float f32x4;

static __device__ __forceinline__ unsigned short f2bf(float x) {
    unsigned u = __float_as_uint(x);
    u = (u + 0x7FFFu + ((u >> 16) & 1u)) >> 16;
    return (unsigned short)u;
}

// ---------------------------------------------------------------------------
// prep_e: eb (bf16, pre-XOR-swizzled within each 512B row) + en exact pairwise
// ---------------------------------------------------------------------------
__global__ __launch_bounds__(64) void prep_e(const float* __restrict__ emb,
                                             unsigned char* __restrict__ ebB,
                                             float* __restrict__ en) {
    int e = blockIdx.x * 64 + threadIdx.x;
    if (e >= NP) return;
    unsigned base = (unsigned)e * 512u;
    unsigned x = ((unsigned)e & 7u) << 4;
    if (e < NE) {
        const float* row = emb + (size_t)e * ZD;
        for (int k = 0; k < ZD; k += 2) {  // 2k%4==0, pair stays in same dword
            unsigned off = (base + 2u * k) ^ x;
            *(unsigned short*)(ebB + off)     = f2bf(row[k]);
            *(unsigned short*)(ebB + off + 2) = f2bf(row[k + 1]);
        }
        float r[8];
        #pragma unroll
        for (int j = 0; j < 8; ++j) { float v = row[j]; r[j] = __fmul_rn(v, v); }
        for (int i = 8; i < 128; i += 8)
            #pragma unroll
            for (int j = 0; j < 8; ++j) { float v = row[i + j]; r[j] = __fadd_rn(r[j], __fmul_rn(v, v)); }
        float s1 = __fadd_rn(__fadd_rn(__fadd_rn(r[0], r[1]), __fadd_rn(r[2], r[3])),
                             __fadd_rn(__fadd_rn(r[4], r[5]), __fadd_rn(r[6], r[7])));
        #pragma unroll
        for (int j = 0; j < 8; ++j) { float v = row[128 + j]; r[j] = __fmul_rn(v, v); }
        for (int i = 136; i < 256; i += 8)
            #pragma unroll
            for (int j = 0; j < 8; ++j) { float v = row[i + j]; r[j] = __fadd_rn(r[j], __fmul_rn(v, v)); }
        float s2 = __fadd_rn(__fadd_rn(__fadd_rn(r[0], r[1]), __fadd_rn(r[2], r[3])),
                             __fadd_rn(__fadd_rn(r[4], r[5]), __fadd_rn(r[6], r[7])));
        en[e] = __fadd_rn(s1, s2);
    } else {
        for (int k = 0; k < 128; ++k) *(unsigned*)(ebB + base + 4u * k) = 0u;
        en[e] = __builtin_inff();
    }
}

// ---------------------------------------------------------------------------
// prep_h: hb (bf16 rows, stored in out_q region, row stride 512 ushorts) and
// hn (exact numpy-pairwise, stored in out_i region as float bits)
// ---------------------------------------------------------------------------
__global__ __launch_bounds__(256) void prep_h(const float* __restrict__ h,
                                              unsigned short* __restrict__ hb,
                                              float* __restrict__ hn) {
    __shared__ float L[64][257];
    const int t = threadIdx.x;
    const long row0 = (long)blockIdx.x * 64;
    const int kq = (t & 63) * 4;
    const int rq = t >> 6;
    #pragma unroll
    for (int p = 0; p < 16; ++p) {
        int row = p * 4 + rq;
        float4 v = *(const float4*)(h + (row0 + row) * ZD + kq);
        L[row][kq] = v.x; L[row][kq + 1] = v.y; L[row][kq + 2] = v.z; L[row][kq + 3] = v.w;
    }
    __syncthreads();
    #pragma unroll
    for (int p = 0; p < 16; ++p) {
        int row = p * 4 + rq;
        ushort4 o;
        o.x = f2bf(L[row][kq]);     o.y = f2bf(L[row][kq + 1]);
        o.z = f2bf(L[row][kq + 2]); o.w = f2bf(L[row][kq + 3]);
        *(ushort4*)(hb + (row0 + row) * 512 + kq) = o;
    }
    if (t < 64) {
        float r[8];
        #pragma unroll
        for (int j = 0; j < 8; ++j) { float v = L[t][j]; r[j] = __fmul_rn(v, v); }
        for (int i = 8; i < 128; i += 8)
            #pragma unroll
            for (int j = 0; j < 8; ++j) { float v = L[t][i + j]; r[j] = __fadd_rn(r[j], __fmul_rn(v, v)); }
        float s1 = __fadd_rn(__fadd_rn(__fadd_rn(r[0], r[1]), __fadd_rn(r[2], r[3])),
                             __fadd_rn(__fadd_rn(r[4], r[5]), __fadd_rn(r[6], r[7])));
        #pragma unroll
        for (int j = 0; j < 8; ++j) { float v = L[t][128 + j]; r[j] = __fmul_rn(v, v); }
        for (int i = 136; i < 256; i += 8)
            #pragma unroll
            for (int j = 0; j < 8; ++j) { float v = L[t][i + j]; r[j] = __fadd_rn(r[j], __fmul_rn(v, v)); }
        float s2 = __fadd_rn(__fadd_rn(__fadd_rn(r[0], r[1]), __fadd_rn(r[2], r[3])),
                             __fadd_rn(__fadd_rn(r[4], r[5]), __fadd_rn(r[6], r[7])));
        hn[row0 + t] = __fadd_rn(s1, s2);
    }
}

// ---------------------------------------------------------------------------
// K1 main: R16 verbatim (best: 8 x 64KB chunks, 66 KB LDS -> 2 blocks/CU,
// #pragma unroll 1 on c/nt loops to block the full-unroll spill).
// Marker epilogue: cnt==1 -> out_l[r]=besti; verify -> -(cnt) + record;
// exhaust -> -99.
// ---------------------------------------------------------------------------
__global__ __launch_bounds__(1024, 4) void vq_main(const float* __restrict__ h,
                                                   const float* __restrict__ emb,
                                                   const unsigned char* __restrict__ ebB,
                                                   const float* __restrict__ en,
                                                   float* out, int M) {
    extern __shared__ char lds[];
    char* BsB = lds;                          // 65536 B swizzled bf16 chunk
    float* en_s = (float*)(lds + 65536);      // 128 floats

    const int t  = threadIdx.x;
    const int lane = t & 63;
    const int wv = t >> 6;                    // 0..15
    const int g  = lane >> 4;                 // 0..3
    const int lg = lane & 15;
    const long rbase = (long)blockIdx.x * 256 + wv * 16;

    const unsigned short* hb = (const unsigned short*)out;    // bf16 h rows
    const float* hnp = out + (size_t)M * ZD;                  // hn values

    short8 afrag[8];
    {
        const unsigned short* hr = hb + (rbase + lg) * 512;
        #pragma unroll
        for (int kt = 0; kt < 8; ++kt)
            afrag[kt] = *(const short8*)(hr + kt * 32 + g * 8);
    }
    float hnr[4], taur[4];
    #pragma unroll
    for (int i = 0; i < 4; ++i) {
        hnr[i] = hnp[rbase + g * 4 + i];
        taur[i] = 1.0e-5f * sqrtf(256.0f * hnr[i]) + 1.0e-3f;
    }

    const float INF = __builtin_inff();
    float bv0[4], bv1[4], bv2[4], bv3[4];
    int   bi0[4], bi1[4], bi2[4], bi3[4];
    #pragma unroll
    for (int i = 0; i < 4; ++i) {
        bv0[i] = INF; bv1[i] = INF; bv2[i] = INF; bv3[i] = INF;
        bi0[i] = 0;   bi1[i] = 0;   bi2[i] = 0;   bi3[i] = 0;
    }

    #pragma unroll 1
    for (int c = 0; c < 8; ++c) {
        { // stage pre-swizzled 64KB chunk linearly (coalesced, conflict-free)
            const uint4* src = (const uint4*)(ebB + (size_t)c * 65536);
            uint4* dst = (uint4*)BsB;
            #pragma unroll
            for (int p = 0; p < 4; ++p) dst[p * 1024 + t] = src[p * 1024 + t];
        }
        if (t < 32) {
            float4 v = *(const float4*)(en + c * 128 + t * 4);
            *(float4*)(en_s + t * 4) = v;
        }
        __syncthreads();

        #pragma unroll 1
        for (int nt = 0; nt < 8; ++nt) {
            f32x4 acc0 = {0.f, 0.f, 0.f, 0.f};
            f32x4 acc1 = {0.f, 0.f, 0.f, 0.f};
            const int nb = nt * 16 + lg;                       // entry in chunk
            const unsigned x = ((unsigned)lg & 7u) << 4;
            const unsigned rowb = (unsigned)nb * 512u;
            #pragma unroll
            for (int kt = 0; kt < 4; ++kt) {
                short8 b0 = *(const short8*)(BsB + ((rowb + (unsigned)kt * 64u + g * 16u) ^ x));
                short8 b1 = *(const short8*)(BsB + ((rowb + (unsigned)(kt + 4) * 64u + g * 16u) ^ x));
                acc0 = __builtin_amdgcn_mfma_f32_16x16x32_bf16(afrag[kt],     b0, acc0, 0, 0, 0);
                acc1 = __builtin_amdgcn_mfma_f32_16x16x32_bf16(afrag[kt + 4], b1, acc1, 0, 0, 0);
            }
            const int eIdx = c * 128 + nb;
            const float ene = en_s[nb];
            #pragma unroll
            for (int i = 0; i < 4; ++i) {
                float dot = __fadd_rn(acc0[i], acc1[i]);
                float d = __fsub_rn(__fadd_rn(hnr[i], ene), __fmul_rn(2.0f, dot));
                if (__any(d < bv3[i])) {
                    bool l3 = d < bv3[i], l2 = d < bv2[i], l1 = d < bv1[i], l0 = d < bv0[i];
                    bv3[i] = l3 ? (l2 ? bv2[i] : d) : bv3[i];
                    bi3[i] = l3 ? (l2 ? bi2[i] : eIdx) : bi3[i];
                    bv2[i] = l2 ? (l1 ? bv1[i] : d) : bv2[i];
                    bi2[i] = l2 ? (l1 ? bi1[i] : eIdx) : bi2[i];
                    bv1[i] = l1 ? (l0 ? bv0[i] : d) : bv1[i];
                    bi1[i] = l1 ? (l0 ? bi0[i] : eIdx) : bi1[i];
                    bv0[i] = l0 ? d : bv0[i];
                    bi0[i] = l0 ? eIdx : bi0[i];
                }
            }
        }
        __syncthreads();
    }

    float* out_q = out;
    float* out_i = out + (size_t)M * ZD;
    float* out_l = out_i + M;

    #pragma unroll 1
    for (int i = 0; i < 4; ++i) {
        const long r = rbase + g * 4 + i;

        float gmin = bv0[i];
        #pragma unroll
        for (int o = 1; o < 16; o <<= 1) gmin = fminf(gmin, __shfl_xor(gmin, o, 64));
        const float thr = gmin + taur[i];

        unsigned b0 = (unsigned)(__ballot(bv0[i] <= thr) >> (g * 16)) & 0xFFFFu;
        unsigned b1 = (unsigned)(__ballot(bv1[i] <= thr) >> (g * 16)) & 0xFFFFu;
        unsigned b2 = (unsigned)(__ballot(bv2[i] <= thr) >> (g * 16)) & 0xFFFFu;
        unsigned b3 = (unsigned)(__ballot(bv3[i] <= thr) >> (g * 16)) & 0xFFFFu;
        const int cnt = __popc(b0) + __popc(b1) + __popc(b2) + __popc(b3);
        const bool ex = (b3 != 0u) || (cnt > 7);

        if (cnt == 1 && !ex) {
            // single in-window candidate: provably the argmin; resolve now.
            if (bv0[i] <= thr) out_l[r] = (float)bi0[i];
        } else if (!ex) {
            float* rec = out_q + (size_t)r * ZD;
            if (lg == 0) {
                rec[0] = (float)cnt;
                out_l[r] = -(float)cnt;          // verify marker
            }
            const unsigned mlt = (1u << lg) - 1u;
            int base = 1;
            if (bv0[i] <= thr) rec[base + __popc(b0 & mlt)] = (float)bi0[i];
            base += __popc(b0);
            if (bv1[i] <= thr) rec[base + __popc(b1 & mlt)] = (float)bi1[i];
            base += __popc(b1);
            if (bv2[i] <= thr) rec[base + __popc(b2 & mlt)] = (float)bi2[i];
        } else {
            if (lg == 0) out_l[r] = -99.0f;      // exhaustive marker
        }
    }
}

// ---------------------------------------------------------------------------
// K2 merged finalize+stream v2 — GROUP-PARALLEL verify:
// each 16-lane group verifies its own row concurrently (was: wave-sequential).
// Only the h row is LDS-staged (per-group 260-fl slice, 16.6 KB/block ->
// 8 blocks/CU, 2x occupancy); candidate e rows are read directly from the
// L2-hot emb (1 MB) inside the chain: h operand is an LDS broadcast within
// the group, <=7 lanes gather <=7 e lines per step — high MLP.
// Chain order / candidate->lane map / lex (d,idx) reduce / exhaustive path /
// stream epilogue: byte-identical semantics to R16.
// ---------------------------------------------------------------------------
__global__ __launch_bounds__(256) void vq_fs(const float* __restrict__ h,
                                             const float* __restrict__ emb,
                                             const float* __restrict__ en,
                                             float* __restrict__ out, int M) {
    extern __shared__ float Lall[];          // 4 waves x 4 rows x 260 floats
    const int t    = threadIdx.x;
    const int wv   = t >> 6;      // 0..3
    const int lane = t & 63;
    const int g    = lane >> 4;   // 0..3
    const int lg   = lane & 15;
    float* Lw = Lall + wv * (4 * 260);

    float* out_q = out;
    float* out_i = out + (size_t)M * ZD;
    float* out_l = out_i + M;
    const float INF = __builtin_inff();

    const long r = (long)blockIdx.x * 16 + wv * 4 + g;   // this group's row
    const float mk = out_l[r];                            // marker/besti
    int besti = (mk >= 0.f) ? (int)mk : 0;
    const bool needv = (mk < 0.f) && (mk > -50.f);        // 2..7 candidates

    // ---- phase 1: stage verify rows' h (all groups concurrently) ----
    if (needv) {
        #pragma unroll
        for (int q4 = 0; q4 < 4; ++q4) {
            int k = q4 * 64 + lg * 4;                     // 256B coalesced/group
            float4 v = *(const float4*)(h + (size_t)r * ZD + k);
            *(float4*)(Lw + g * 260 + k) = v;
        }
    }
    asm volatile("s_waitcnt lgkmcnt(0)" ::: "memory");

    // ---- phase 2: all groups' candidate chains run concurrently ----
    if (needv) {
        const int cnt = -(int)mk;
        const float* rec = out_q + (size_t)r * ZD;
        const float4 rA = *(const float4*)(rec);          // cnt,i0,i1,i2
        const float4 rB = *(const float4*)(rec + 4);      // i3,i4,i5,i6
        const float hn = out_i[r];
        float bd = INF;
        int   bi = 0x7FFFFFFF;
        if (lg < cnt) {
            const float fq = (lg == 0) ? rA.y : (lg == 1) ? rA.z : (lg == 2) ? rA.w
                           : (lg == 3) ? rB.x : (lg == 4) ? rB.y : (lg == 5) ? rB.z : rB.w;
            const int idx = (int)fq;
            const float* er = emb + (size_t)idx * ZD;
            const float* hl = Lw + g * 260;
            float dot = 0.f;
            #pragma unroll 8
            for (int k = 0; k < ZD; k += 4) {
                float4 ev = *(const float4*)(er + k);
                dot = fmaf(hl[k],     ev.x, dot);
                dot = fmaf(hl[k + 1], ev.y, dot);
                dot = fmaf(hl[k + 2], ev.z, dot);
                dot = fmaf(hl[k + 3], ev.w, dot);
            }
            bd = __fsub_rn(__fadd_rn(hn, en[idx]), __fmul_rn(2.0f, dot));
            bi = idx;
        }
        #pragma unroll
        for (int o = 1; o < 16; o <<= 1) {               // lex (d,idx) min in group
            float ov = __shfl_xor(bd, o, 16);
            int   oi = __shfl_xor(bi, o, 16);
            if (ov < bd || (ov == bd && oi < bi)) { bd = ov; bi = oi; }
        }
        besti = bi;
    }

    // ---- exhaustive rows (ultra-rare): whole-wave, lane-parallel entries ----
    unsigned long long exm = __ballot(mk <= -50.f) & 0x0001000100010001ull;
    while (exm) {
        const int bitpos = (int)(__ffsll(exm) - 1);
        exm &= exm - 1;
        const int wgx = bitpos >> 4;                      // group index 0..3
        const long rx = (long)blockIdx.x * 16 + wv * 4 + wgx;
        const float hnx = out_i[rx];
        const float* hrowx = h + (size_t)rx * ZD;
        float bd = INF;
        int   bi = 0x7FFFFFFF;
        for (int e = lane; e < NE; e += 64) {
            const float* er = emb + (size_t)e * ZD;
            float dot = 0.f;
            #pragma unroll 8
            for (int k = 0; k < ZD; k += 4) {
                float4 hv = *(const float4*)(hrowx + k);
                float4 ev = *(const float4*)(er + k);
                dot = fmaf(hv.x, ev.x, dot);
                dot = fmaf(hv.y, ev.y, dot);
                dot = fmaf(hv.z, ev.z, dot);
                dot = fmaf(hv.w, ev.w, dot);
            }
            float dx = __fsub_rn(__fadd_rn(hnx, en[e]), __fmul_rn(2.0f, dot));
            if (dx < bd || (dx == bd && e < bi)) { bd = dx; bi = e; }
        }
        #pragma unroll
        for (int o = 1; o < 64; o <<= 1) {
            float ov = __shfl_xor(bd, o, 64);
            int   oi = __shfl_xor(bi, o, 64);
            if (ov < bd || (ov == bd && oi < bi)) { bd = ov; bi = oi; }
        }
        if (g == wgx) besti = bi;
    }

    // ---- stream: R1's byte-exact epilogue for this group's row ----
    const float* hrow = h + (size_t)r * ZD;
    const float* erow = emb + (size_t)besti * ZD;
    float csum = 0.0f;
    #pragma unroll
    for (int q4 = 0; q4 < 4; ++q4) {
        int k = lg * 16 + q4 * 4;
        float4 hv = *(const float4*)(hrow + k);
        float4 ev = *(const float4*)(erow + k);
        float dx = __fsub_rn(ev.x, hv.x);
        float dy = __fsub_rn(ev.y, hv.y);
        float dz = __fsub_rn(ev.z, hv.z);
        float dw = __fsub_rn(ev.w, hv.w);
        float4 o;
        o.x = __fadd_rn(hv.x, dx);
        o.y = __fadd_rn(hv.y, dy);
        o.z = __fadd_rn(hv.z, dz);
        o.w = __fadd_rn(hv.w, dw);
        *(float4*)(out_q + (size_t)r * ZD + k) = o;
        csum = fmaf(dx, dx, csum);
        csum = fmaf(dy, dy, csum);
        csum = fmaf(dz, dz, csum);
        csum = fmaf(dw, dw, csum);
    }
    #pragma unroll
    for (int o2 = 1; o2 < 16; o2 <<= 1) csum += __shfl_xor(csum, o2, 64);
    if (lg == 0) {
        float cmean = csum * (1.0f / 256.0f);
        out_i[r] = (float)besti;
        out_l[r] = __fadd_rn(__fmul_rn(cmean, 0.1f), __fmul_rn(cmean, 0.2f));
    }
}

extern "C" void kernel_launch(void* const* d_in, const int* in_sizes, int n_in,
                              void* d_out, int out_size, void* d_ws, size_t ws_size,
                              hipStream_t stream) {
    const float* h   = (const float*)d_in[0];
    const float* emb = (const float*)d_in[1];
    const int M = in_sizes[0] / ZD;   // 131072

    unsigned char* ebB = (unsigned char*)d_ws;               // 512 KB bf16 swizzled
    float* en = (float*)(ebB + (size_t)NP * ZD * 2);         // 4 KB

    float* out = (float*)d_out;
    unsigned short* hb = (unsigned short*)d_out;             // bf16 h in out_q region
    float* hn = out + (size_t)M * ZD;                        // hn in out_i region

    prep_e<<<NP / 64, 64, 0, stream>>>(emb, ebB, en);
    prep_h<<<M / 64, 256, 0, stream>>>(h, hb, hn);

    const size_t lds_bytes = 65536 + 512;                    // 66 KB -> 2 blocks/CU
    (void)hipFuncSetAttribute((const void*)vq_main,
                              hipFuncAttributeMaxDynamicSharedMemorySize,
                              (int)lds_bytes);
    vq_main<<<M / 256, 1024, lds_bytes, stream>>>(h, emb, ebB, en, out, M);

    const size_t fs_lds = 4 * 4 * 260 * sizeof(float);       // 16640 B -> 8 blocks/CU
    vq_fs<<<M / 16, 256, fs_lds, stream>>>(h, emb, en, out, M);
}

// Round 19
// 519.667 us; speedup vs baseline: 1.0584x; 1.0071x over previous
//
#include <hip/hip_runtime.h>

#define ZD 256    // Z_NH
#define NE 1000   // NUM_ENTRY
#define NP 1024   // padded entries

typedef __attribute__((ext_vector_type(8))) short short8;
typedef __attribute__((ext_vector_type(4))) float f32x4;

static __device__ __forceinline__ unsigned short f2bf(float x) {
    unsigned u = __float_as_uint(x);
    u = (u + 0x7FFFu + ((u >> 16) & 1u)) >> 16;
    return (unsigned short)u;
}

// ---------------------------------------------------------------------------
// prep_e: eb (bf16, pre-XOR-swizzled within each 512B row) + en exact pairwise
// ---------------------------------------------------------------------------
__global__ __launch_bounds__(64) void prep_e(const float* __restrict__ emb,
                                             unsigned char* __restrict__ ebB,
                                             float* __restrict__ en) {
    int e = blockIdx.x * 64 + threadIdx.x;
    if (e >= NP) return;
    unsigned base = (unsigned)e * 512u;
    unsigned x = ((unsigned)e & 7u) << 4;
    if (e < NE) {
        const float* row = emb + (size_t)e * ZD;
        for (int k = 0; k < ZD; k += 2) {  // 2k%4==0, pair stays in same dword
            unsigned off = (base + 2u * k) ^ x;
            *(unsigned short*)(ebB + off)     = f2bf(row[k]);
            *(unsigned short*)(ebB + off + 2) = f2bf(row[k + 1]);
        }
        float r[8];
        #pragma unroll
        for (int j = 0; j < 8; ++j) { float v = row[j]; r[j] = __fmul_rn(v, v); }
        for (int i = 8; i < 128; i += 8)
            #pragma unroll
            for (int j = 0; j < 8; ++j) { float v = row[i + j]; r[j] = __fadd_rn(r[j], __fmul_rn(v, v)); }
        float s1 = __fadd_rn(__fadd_rn(__fadd_rn(r[0], r[1]), __fadd_rn(r[2], r[3])),
                             __fadd_rn(__fadd_rn(r[4], r[5]), __fadd_rn(r[6], r[7])));
        #pragma unroll
        for (int j = 0; j < 8; ++j) { float v = row[128 + j]; r[j] = __fmul_rn(v, v); }
        for (int i = 136; i < 256; i += 8)
            #pragma unroll
            for (int j = 0; j < 8; ++j) { float v = row[i + j]; r[j] = __fadd_rn(r[j], __fmul_rn(v, v)); }
        float s2 = __fadd_rn(__fadd_rn(__fadd_rn(r[0], r[1]), __fadd_rn(r[2], r[3])),
                             __fadd_rn(__fadd_rn(r[4], r[5]), __fadd_rn(r[6], r[7])));
        en[e] = __fadd_rn(s1, s2);
    } else {
        for (int k = 0; k < 128; ++k) *(unsigned*)(ebB + base + 4u * k) = 0u;
        en[e] = __builtin_inff();
    }
}

// ---------------------------------------------------------------------------
// prep_h: hb (bf16 rows, stored in out_q region, row stride 512 ushorts) and
// hn (exact numpy-pairwise, stored in out_i region as float bits)
// ---------------------------------------------------------------------------
__global__ __launch_bounds__(256) void prep_h(const float* __restrict__ h,
                                              unsigned short* __restrict__ hb,
                                              float* __restrict__ hn) {
    __shared__ float L[64][257];
    const int t = threadIdx.x;
    const long row0 = (long)blockIdx.x * 64;
    const int kq = (t & 63) * 4;
    const int rq = t >> 6;
    #pragma unroll
    for (int p = 0; p < 16; ++p) {
        int row = p * 4 + rq;
        float4 v = *(const float4*)(h + (row0 + row) * ZD + kq);
        L[row][kq] = v.x; L[row][kq + 1] = v.y; L[row][kq + 2] = v.z; L[row][kq + 3] = v.w;
    }
    __syncthreads();
    #pragma unroll
    for (int p = 0; p < 16; ++p) {
        int row = p * 4 + rq;
        ushort4 o;
        o.x = f2bf(L[row][kq]);     o.y = f2bf(L[row][kq + 1]);
        o.z = f2bf(L[row][kq + 2]); o.w = f2bf(L[row][kq + 3]);
        *(ushort4*)(hb + (row0 + row) * 512 + kq) = o;
    }
    if (t < 64) {
        float r[8];
        #pragma unroll
        for (int j = 0; j < 8; ++j) { float v = L[t][j]; r[j] = __fmul_rn(v, v); }
        for (int i = 8; i < 128; i += 8)
            #pragma unroll
            for (int j = 0; j < 8; ++j) { float v = L[t][i + j]; r[j] = __fadd_rn(r[j], __fmul_rn(v, v)); }
        float s1 = __fadd_rn(__fadd_rn(__fadd_rn(r[0], r[1]), __fadd_rn(r[2], r[3])),
                             __fadd_rn(__fadd_rn(r[4], r[5]), __fadd_rn(r[6], r[7])));
        #pragma unroll
        for (int j = 0; j < 8; ++j) { float v = L[t][128 + j]; r[j] = __fmul_rn(v, v); }
        for (int i = 136; i < 256; i += 8)
            #pragma unroll
            for (int j = 0; j < 8; ++j) { float v = L[t][i + j]; r[j] = __fadd_rn(r[j], __fmul_rn(v, v)); }
        float s2 = __fadd_rn(__fadd_rn(__fadd_rn(r[0], r[1]), __fadd_rn(r[2], r[3])),
                             __fadd_rn(__fadd_rn(r[4], r[5]), __fadd_rn(r[6], r[7])));
        hn[row0 + t] = __fadd_rn(s1, s2);
    }
}

// ---------------------------------------------------------------------------
// K1 main: R16 verbatim (best: 8 x 64KB chunks, 66 KB LDS -> 2 blocks/CU,
// #pragma unroll 1 on c/nt loops to block the full-unroll spill).
// Marker epilogue: cnt==1 -> out_l[r]=besti; verify -> -(cnt) + record;
// exhaust -> -99.
// ---------------------------------------------------------------------------
__global__ __launch_bounds__(1024, 4) void vq_main(const float* __restrict__ h,
                                                   const float* __restrict__ emb,
                                                   const unsigned char* __restrict__ ebB,
                                                   const float* __restrict__ en,
                                                   float* out, int M) {
    extern __shared__ char lds[];
    char* BsB = lds;                          // 65536 B swizzled bf16 chunk
    float* en_s = (float*)(lds + 65536);      // 128 floats

    const int t  = threadIdx.x;
    const int lane = t & 63;
    const int wv = t >> 6;                    // 0..15
    const int g  = lane >> 4;                 // 0..3
    const int lg = lane & 15;
    const long rbase = (long)blockIdx.x * 256 + wv * 16;

    const unsigned short* hb = (const unsigned short*)out;    // bf16 h rows
    const float* hnp = out + (size_t)M * ZD;                  // hn values

    short8 afrag[8];
    {
        const unsigned short* hr = hb + (rbase + lg) * 512;
        #pragma unroll
        for (int kt = 0; kt < 8; ++kt)
            afrag[kt] = *(const short8*)(hr + kt * 32 + g * 8);
    }
    float hnr[4], taur[4];
    #pragma unroll
    for (int i = 0; i < 4; ++i) {
        hnr[i] = hnp[rbase + g * 4 + i];
        taur[i] = 1.0e-5f * sqrtf(256.0f * hnr[i]) + 1.0e-3f;
    }

    const float INF = __builtin_inff();
    float bv0[4], bv1[4], bv2[4], bv3[4];
    int   bi0[4], bi1[4], bi2[4], bi3[4];
    #pragma unroll
    for (int i = 0; i < 4; ++i) {
        bv0[i] = INF; bv1[i] = INF; bv2[i] = INF; bv3[i] = INF;
        bi0[i] = 0;   bi1[i] = 0;   bi2[i] = 0;   bi3[i] = 0;
    }

    #pragma unroll 1
    for (int c = 0; c < 8; ++c) {
        { // stage pre-swizzled 64KB chunk linearly (coalesced, conflict-free)
            const uint4* src = (const uint4*)(ebB + (size_t)c * 65536);
            uint4* dst = (uint4*)BsB;
            #pragma unroll
            for (int p = 0; p < 4; ++p) dst[p * 1024 + t] = src[p * 1024 + t];
        }
        if (t < 32) {
            float4 v = *(const float4*)(en + c * 128 + t * 4);
            *(float4*)(en_s + t * 4) = v;
        }
        __syncthreads();

        #pragma unroll 1
        for (int nt = 0; nt < 8; ++nt) {
            f32x4 acc0 = {0.f, 0.f, 0.f, 0.f};
            f32x4 acc1 = {0.f, 0.f, 0.f, 0.f};
            const int nb = nt * 16 + lg;                       // entry in chunk
            const unsigned x = ((unsigned)lg & 7u) << 4;
            const unsigned rowb = (unsigned)nb * 512u;
            #pragma unroll
            for (int kt = 0; kt < 4; ++kt) {
                short8 b0 = *(const short8*)(BsB + ((rowb + (unsigned)kt * 64u + g * 16u) ^ x));
                short8 b1 = *(const short8*)(BsB + ((rowb + (unsigned)(kt + 4) * 64u + g * 16u) ^ x));
                acc0 = __builtin_amdgcn_mfma_f32_16x16x32_bf16(afrag[kt],     b0, acc0, 0, 0, 0);
                acc1 = __builtin_amdgcn_mfma_f32_16x16x32_bf16(afrag[kt + 4], b1, acc1, 0, 0, 0);
            }
            const int eIdx = c * 128 + nb;
            const float ene = en_s[nb];
            #pragma unroll
            for (int i = 0; i < 4; ++i) {
                float dot = __fadd_rn(acc0[i], acc1[i]);
                float d = __fsub_rn(__fadd_rn(hnr[i], ene), __fmul_rn(2.0f, dot));
                if (__any(d < bv3[i])) {
                    bool l3 = d < bv3[i], l2 = d < bv2[i], l1 = d < bv1[i], l0 = d < bv0[i];
                    bv3[i] = l3 ? (l2 ? bv2[i] : d) : bv3[i];
                    bi3[i] = l3 ? (l2 ? bi2[i] : eIdx) : bi3[i];
                    bv2[i] = l2 ? (l1 ? bv1[i] : d) : bv2[i];
                    bi2[i] = l2 ? (l1 ? bi1[i] : eIdx) : bi2[i];
                    bv1[i] = l1 ? (l0 ? bv0[i] : d) : bv1[i];
                    bi1[i] = l1 ? (l0 ? bi0[i] : eIdx) : bi1[i];
                    bv0[i] = l0 ? d : bv0[i];
                    bi0[i] = l0 ? eIdx : bi0[i];
                }
            }
        }
        __syncthreads();
    }

    float* out_q = out;
    float* out_i = out + (size_t)M * ZD;
    float* out_l = out_i + M;

    #pragma unroll 1
    for (int i = 0; i < 4; ++i) {
        const long r = rbase + g * 4 + i;

        float gmin = bv0[i];
        #pragma unroll
        for (int o = 1; o < 16; o <<= 1) gmin = fminf(gmin, __shfl_xor(gmin, o, 64));
        const float thr = gmin + taur[i];

        unsigned b0 = (unsigned)(__ballot(bv0[i] <= thr) >> (g * 16)) & 0xFFFFu;
        unsigned b1 = (unsigned)(__ballot(bv1[i] <= thr) >> (g * 16)) & 0xFFFFu;
        unsigned b2 = (unsigned)(__ballot(bv2[i] <= thr) >> (g * 16)) & 0xFFFFu;
        unsigned b3 = (unsigned)(__ballot(bv3[i] <= thr) >> (g * 16)) & 0xFFFFu;
        const int cnt = __popc(b0) + __popc(b1) + __popc(b2) + __popc(b3);
        const bool ex = (b3 != 0u) || (cnt > 7);

        if (cnt == 1 && !ex) {
            // single in-window candidate: provably the argmin; resolve now.
            if (bv0[i] <= thr) out_l[r] = (float)bi0[i];
        } else if (!ex) {
            float* rec = out_q + (size_t)r * ZD;
            if (lg == 0) {
                rec[0] = (float)cnt;
                out_l[r] = -(float)cnt;          // verify marker
            }
            const unsigned mlt = (1u << lg) - 1u;
            int base = 1;
            if (bv0[i] <= thr) rec[base + __popc(b0 & mlt)] = (float)bi0[i];
            base += __popc(b0);
            if (bv1[i] <= thr) rec[base + __popc(b1 & mlt)] = (float)bi1[i];
            base += __popc(b1);
            if (bv2[i] <= thr) rec[base + __popc(b2 & mlt)] = (float)bi2[i];
        } else {
            if (lg == 0) out_l[r] = -99.0f;      // exhaustive marker
        }
    }
}

// ---------------------------------------------------------------------------
// K2 merged finalize+stream v3 — R16 structure with BURST staging:
// all groups' records/hn prefetched concurrently at wave start; per verify
// row, h + 7 candidate e rows (clamp-padded duplicates; unused slots never
// read) are loaded with 8 concurrent coalesced 1KB loads -> ONE latency
// exposure instead of ~cnt serialized ones. Chains from LDS, lex (d,idx)
// reduce, exhaustive path and stream epilogue byte-identical to R16.
// ---------------------------------------------------------------------------
__global__ __launch_bounds__(256) void vq_fs(const float* __restrict__ h,
                                             const float* __restrict__ emb,
                                             const float* __restrict__ en,
                                             float* __restrict__ out, int M) {
    extern __shared__ float Lall[];          // 4 waves x 8 rows x 260 floats
    const int t    = threadIdx.x;
    const int wv   = t >> 6;      // 0..3
    const int lane = t & 63;
    const int g    = lane >> 4;   // 0..3
    const int lg   = lane & 15;
    float* Lw = Lall + wv * (8 * 260);

    float* out_q = out;
    float* out_i = out + (size_t)M * ZD;
    float* out_l = out_i + M;
    const float INF = __builtin_inff();

    const long r = (long)blockIdx.x * 16 + wv * 4 + g;   // this group's row
    const float mk = out_l[r];                            // marker/besti
    int besti = (mk >= 0.f) ? (int)mk : 0;
    const bool needv = (mk < 0.f) && (mk > -50.f);

    // ---- concurrent prefetch: each group loads ITS row's record + hn ----
    float4 rAg = {0.f, 0.f, 0.f, 0.f}, rBg = {0.f, 0.f, 0.f, 0.f};
    float hng = 0.f;
    if (needv) {
        const float* rec = out_q + (size_t)r * ZD;
        rAg = *(const float4*)(rec);          // cnt,i0,i1,i2
        rBg = *(const float4*)(rec + 4);      // i3,i4,i5,i6
        hng = out_i[r];
    }
    const int cc0 = (int)rAg.y, cc1 = (int)rAg.z, cc2 = (int)rAg.w;
    const int cc3 = (int)rBg.x, cc4 = (int)rBg.y, cc5 = (int)rBg.z, cc6 = (int)rBg.w;

    // ---- wave-level: resolve verify rows, one at a time, burst-staged ----
    unsigned long long vb = __ballot(needv);
    #pragma unroll 1
    for (int gx = 0; gx < 4; ++gx) {
        if (!((vb >> (gx * 16)) & 1ull)) continue;
        const long rx = (long)blockIdx.x * 16 + wv * 4 + gx;
        const int  cntx = -(int)__shfl(mk, gx * 16, 64);   // 2..7
        const float hnx = __shfl(hng, gx * 16, 64);
        const int c0 = __shfl(cc0, gx * 16, 64);
        const int c1 = __shfl(cc1, gx * 16, 64);
        const int c2 = __shfl(cc2, gx * 16, 64);
        const int c3 = __shfl(cc3, gx * 16, 64);
        const int c4 = __shfl(cc4, gx * 16, 64);
        const int c5 = __shfl(cc5, gx * 16, 64);
        const int c6 = __shfl(cc6, gx * 16, 64);
        // clamp-pad: slots >= cntx duplicate c0 (never read; lane<cntx guard)
        const int j1 = (cntx > 1) ? c1 : c0;
        const int j2 = (cntx > 2) ? c2 : c0;
        const int j3 = (cntx > 3) ? c3 : c0;
        const int j4 = (cntx > 4) ? c4 : c0;
        const int j5 = (cntx > 5) ? c5 : c0;
        const int j6 = (cntx > 6) ? c6 : c0;

        asm volatile("s_waitcnt lgkmcnt(0)" ::: "memory");  // WAR vs prev row

        // burst: 8 concurrent coalesced 1KB loads (distinct registers)
        float4 hv4 = *(const float4*)(h + (size_t)rx * ZD + lane * 4);
        float4 e0v = *(const float4*)(emb + (size_t)c0 * ZD + lane * 4);
        float4 e1v = *(const float4*)(emb + (size_t)j1 * ZD + lane * 4);
        float4 e2v = *(const float4*)(emb + (size_t)j2 * ZD + lane * 4);
        float4 e3v = *(const float4*)(emb + (size_t)j3 * ZD + lane * 4);
        float4 e4v = *(const float4*)(emb + (size_t)j4 * ZD + lane * 4);
        float4 e5v = *(const float4*)(emb + (size_t)j5 * ZD + lane * 4);
        float4 e6v = *(const float4*)(emb + (size_t)j6 * ZD + lane * 4);
        *(float4*)(Lw + lane * 4)           = hv4;
        *(float4*)(Lw + 1 * 260 + lane * 4) = e0v;
        *(float4*)(Lw + 2 * 260 + lane * 4) = e1v;
        *(float4*)(Lw + 3 * 260 + lane * 4) = e2v;
        *(float4*)(Lw + 4 * 260 + lane * 4) = e3v;
        *(float4*)(Lw + 5 * 260 + lane * 4) = e4v;
        *(float4*)(Lw + 6 * 260 + lane * 4) = e5v;
        *(float4*)(Lw + 7 * 260 + lane * 4) = e6v;
        asm volatile("s_waitcnt lgkmcnt(0)" ::: "memory");  // RAW

        float bd = INF;
        int   bi = 0x7FFFFFFF;
        if (lane < cntx) {
            const int idx = (lane == 0) ? c0 : (lane == 1) ? j1 : (lane == 2) ? j2
                          : (lane == 3) ? j3 : (lane == 4) ? j4 : (lane == 5) ? j5 : j6;
            const float* hl = Lw;
            const float* el = Lw + (1 + lane) * 260;
            float dot = 0.f;
            #pragma unroll 8
            for (int k = 0; k < ZD; k += 4) {
                dot = fmaf(hl[k],     el[k],     dot);
                dot = fmaf(hl[k + 1], el[k + 1], dot);
                dot = fmaf(hl[k + 2], el[k + 2], dot);
                dot = fmaf(hl[k + 3], el[k + 3], dot);
            }
            bd = __fsub_rn(__fadd_rn(hnx, en[idx]), __fmul_rn(2.0f, dot));
            bi = idx;
        }
        #pragma unroll
        for (int o = 1; o < 8; o <<= 1) {  // lex (d,idx) min, lanes 0..7
            float ov = __shfl_xor(bd, o, 8);
            int   oi = __shfl_xor(bi, o, 8);
            if (ov < bd || (ov == bd && oi < bi)) { bd = ov; bi = oi; }
        }
        const int bix = __shfl(bi, 0, 64);
        if (g == gx) besti = bix;
    }

    // ---- exhaustive rows (ultra-rare): whole-wave, lane-parallel entries ----
    unsigned long long exm = __ballot(mk <= -50.f) & 0x0001000100010001ull;
    while (exm) {
        const int bitpos = (int)(__ffsll(exm) - 1);
        exm &= exm - 1;
        const int wgx = bitpos >> 4;                      // group index 0..3
        const long rx = (long)blockIdx.x * 16 + wv * 4 + wgx;
        const float hnx = out_i[rx];
        const float* hrowx = h + (size_t)rx * ZD;
        float bd = INF;
        int   bi = 0x7FFFFFFF;
        for (int e = lane; e < NE; e += 64) {
            const float* er = emb + (size_t)e * ZD;
            float dot = 0.f;
            #pragma unroll 8
            for (int k = 0; k < ZD; k += 4) {
                float4 hv = *(const float4*)(hrowx + k);
                float4 ev = *(const float4*)(er + k);
                dot = fmaf(hv.x, ev.x, dot);
                dot = fmaf(hv.y, ev.y, dot);
                dot = fmaf(hv.z, ev.z, dot);
                dot = fmaf(hv.w, ev.w, dot);
            }
            float dx = __fsub_rn(__fadd_rn(hnx, en[e]), __fmul_rn(2.0f, dot));
            if (dx < bd || (dx == bd && e < bi)) { bd = dx; bi = e; }
        }
        #pragma unroll
        for (int o = 1; o < 64; o <<= 1) {
            float ov = __shfl_xor(bd, o, 64);
            int   oi = __shfl_xor(bi, o, 64);
            if (ov < bd || (ov == bd && oi < bi)) { bd = ov; bi = oi; }
        }
        if (g == wgx) besti = bi;
    }

    // ---- stream: R1's byte-exact epilogue for this group's row ----
    const float* hrow = h + (size_t)r * ZD;
    const float* erow = emb + (size_t)besti * ZD;
    float csum = 0.0f;
    #pragma unroll
    for (int q4 = 0; q4 < 4; ++q4) {
        int k = lg * 16 + q4 * 4;
        float4 hv = *(const float4*)(hrow + k);
        float4 ev = *(const float4*)(erow + k);
        float dx = __fsub_rn(ev.x, hv.x);
        float dy = __fsub_rn(ev.y, hv.y);
        float dz = __fsub_rn(ev.z, hv.z);
        float dw = __fsub_rn(ev.w, hv.w);
        float4 o;
        o.x = __fadd_rn(hv.x, dx);
        o.y = __fadd_rn(hv.y, dy);
        o.z = __fadd_rn(hv.z, dz);
        o.w = __fadd_rn(hv.w, dw);
        *(float4*)(out_q + (size_t)r * ZD + k) = o;
        csum = fmaf(dx, dx, csum);
        csum = fmaf(dy, dy, csum);
        csum = fmaf(dz, dz, csum);
        csum = fmaf(dw, dw, csum);
    }
    #pragma unroll
    for (int o2 = 1; o2 < 16; o2 <<= 1) csum += __shfl_xor(csum, o2, 64);
    if (lg == 0) {
        float cmean = csum * (1.0f / 256.0f);
        out_i[r] = (float)besti;
        out_l[r] = __fadd_rn(__fmul_rn(cmean, 0.1f), __fmul_rn(cmean, 0.2f));
    }
}

extern "C" void kernel_launch(void* const* d_in, const int* in_sizes, int n_in,
                              void* d_out, int out_size, void* d_ws, size_t ws_size,
                              hipStream_t stream) {
    const float* h   = (const float*)d_in[0];
    const float* emb = (const float*)d_in[1];
    const int M = in_sizes[0] / ZD;   // 131072

    unsigned char* ebB = (unsigned char*)d_ws;               // 512 KB bf16 swizzled
    float* en = (float*)(ebB + (size_t)NP * ZD * 2);         // 4 KB

    float* out = (float*)d_out;
    unsigned short* hb = (unsigned short*)d_out;             // bf16 h in out_q region
    float* hn = out + (size_t)M * ZD;                        // hn in out_i region

    prep_e<<<NP / 64, 64, 0, stream>>>(emb, ebB, en);
    prep_h<<<M / 64, 256, 0, stream>>>(h, hb, hn);

    const size_t lds_bytes = 65536 + 512;                    // 66 KB -> 2 blocks/CU
    (void)hipFuncSetAttribute((const void*)vq_main,
                              hipFuncAttributeMaxDynamicSharedMemorySize,
                              (int)lds_bytes);
    vq_main<<<M / 256, 1024, lds_bytes, stream>>>(h, emb, ebB, en, out, M);

    const size_t fs_lds = 4 * 8 * 260 * sizeof(float);       // 33280 B
    vq_fs<<<M / 16, 256, fs_lds, stream>>>(h, emb, en, out, M);
}

// Round 20
// 348.609 us; speedup vs baseline: 1.5777x; 1.4907x over previous
//
#include <hip/hip_runtime.h>

#define ZD 256    // Z_NH
#define NE 1000   // NUM_ENTRY
#define NP 1024   // padded entries

typedef __attribute__((ext_vector_type(8))) short short8;
typedef __attribute__((ext_vector_type(4))) float f32x4;

static __device__ __forceinline__ unsigned short f2bf(float x) {
    unsigned u = __float_as_uint(x);
    u = (u + 0x7FFFu + ((u >> 16) & 1u)) >> 16;
    return (unsigned short)u;
}

// ---------------------------------------------------------------------------
// prep_e: eb (bf16, pre-XOR-swizzled within each 512B row) + en exact pairwise
// ---------------------------------------------------------------------------
__global__ __launch_bounds__(64) void prep_e(const float* __restrict__ emb,
                                             unsigned char* __restrict__ ebB,
                                             float* __restrict__ en) {
    int e = blockIdx.x * 64 + threadIdx.x;
    if (e >= NP) return;
    unsigned base = (unsigned)e * 512u;
    unsigned x = ((unsigned)e & 7u) << 4;
    if (e < NE) {
        const float* row = emb + (size_t)e * ZD;
        for (int k = 0; k < ZD; k += 2) {  // 2k%4==0, pair stays in same dword
            unsigned off = (base + 2u * k) ^ x;
            *(unsigned short*)(ebB + off)     = f2bf(row[k]);
            *(unsigned short*)(ebB + off + 2) = f2bf(row[k + 1]);
        }
        float r[8];
        #pragma unroll
        for (int j = 0; j < 8; ++j) { float v = row[j]; r[j] = __fmul_rn(v, v); }
        for (int i = 8; i < 128; i += 8)
            #pragma unroll
            for (int j = 0; j < 8; ++j) { float v = row[i + j]; r[j] = __fadd_rn(r[j], __fmul_rn(v, v)); }
        float s1 = __fadd_rn(__fadd_rn(__fadd_rn(r[0], r[1]), __fadd_rn(r[2], r[3])),
                             __fadd_rn(__fadd_rn(r[4], r[5]), __fadd_rn(r[6], r[7])));
        #pragma unroll
        for (int j = 0; j < 8; ++j) { float v = row[128 + j]; r[j] = __fmul_rn(v, v); }
        for (int i = 136; i < 256; i += 8)
            #pragma unroll
            for (int j = 0; j < 8; ++j) { float v = row[i + j]; r[j] = __fadd_rn(r[j], __fmul_rn(v, v)); }
        float s2 = __fadd_rn(__fadd_rn(__fadd_rn(r[0], r[1]), __fadd_rn(r[2], r[3])),
                             __fadd_rn(__fadd_rn(r[4], r[5]), __fadd_rn(r[6], r[7])));
        en[e] = __fadd_rn(s1, s2);
    } else {
        for (int k = 0; k < 128; ++k) *(unsigned*)(ebB + base + 4u * k) = 0u;
        en[e] = __builtin_inff();
    }
}

// ---------------------------------------------------------------------------
// prep_h: hb (bf16 rows, stored in out_q region, row stride 512 ushorts) and
// hn (exact numpy-pairwise, stored in out_i region as float bits)
// ---------------------------------------------------------------------------
__global__ __launch_bounds__(256) void prep_h(const float* __restrict__ h,
                                              unsigned short* __restrict__ hb,
                                              float* __restrict__ hn) {
    __shared__ float L[64][257];
    const int t = threadIdx.x;
    const long row0 = (long)blockIdx.x * 64;
    const int kq = (t & 63) * 4;
    const int rq = t >> 6;
    #pragma unroll
    for (int p = 0; p < 16; ++p) {
        int row = p * 4 + rq;
        float4 v = *(const float4*)(h + (row0 + row) * ZD + kq);
        L[row][kq] = v.x; L[row][kq + 1] = v.y; L[row][kq + 2] = v.z; L[row][kq + 3] = v.w;
    }
    __syncthreads();
    #pragma unroll
    for (int p = 0; p < 16; ++p) {
        int row = p * 4 + rq;
        ushort4 o;
        o.x = f2bf(L[row][kq]);     o.y = f2bf(L[row][kq + 1]);
        o.z = f2bf(L[row][kq + 2]); o.w = f2bf(L[row][kq + 3]);
        *(ushort4*)(hb + (row0 + row) * 512 + kq) = o;
    }
    if (t < 64) {
        float r[8];
        #pragma unroll
        for (int j = 0; j < 8; ++j) { float v = L[t][j]; r[j] = __fmul_rn(v, v); }
        for (int i = 8; i < 128; i += 8)
            #pragma unroll
            for (int j = 0; j < 8; ++j) { float v = L[t][i + j]; r[j] = __fadd_rn(r[j], __fmul_rn(v, v)); }
        float s1 = __fadd_rn(__fadd_rn(__fadd_rn(r[0], r[1]), __fadd_rn(r[2], r[3])),
                             __fadd_rn(__fadd_rn(r[4], r[5]), __fadd_rn(r[6], r[7])));
        #pragma unroll
        for (int j = 0; j < 8; ++j) { float v = L[t][128 + j]; r[j] = __fmul_rn(v, v); }
        for (int i = 136; i < 256; i += 8)
            #pragma unroll
            for (int j = 0; j < 8; ++j) { float v = L[t][i + j]; r[j] = __fadd_rn(r[j], __fmul_rn(v, v)); }
        float s2 = __fadd_rn(__fadd_rn(__fadd_rn(r[0], r[1]), __fadd_rn(r[2], r[3])),
                             __fadd_rn(__fadd_rn(r[4], r[5]), __fadd_rn(r[6], r[7])));
        hn[row0 + t] = __fadd_rn(s1, s2);
    }
}

// ---------------------------------------------------------------------------
// K1 main: R16 verbatim (8 x 64KB chunks, 66 KB LDS -> 2 blocks/CU,
// #pragma unroll 1 on c/nt loops to block the full-unroll spill) with ONE
// change: derived tau. 1-term bf16 approx error bound: 2*Delta <=
// 2*(2*2^-8*sqrt(hn*en) + ulp(256) roundings) ~= 2.6e-4 worst-case on this
// data; tau = 2e-6*sqrt(256*hn)+2.5e-4 ~= 7.6e-4 keeps a 2.9x margin and is
// 4.7x tighter than the inherited 3.56e-3 -> verify set shrinks ~4x at ZERO
// main-loop cost. Marker epilogue: cnt==1 -> out_l[r]=besti; verify ->
// -(cnt) + record; exhaust -> -99.
// ---------------------------------------------------------------------------
__global__ __launch_bounds__(1024, 4) void vq_main(const float* __restrict__ h,
                                                   const float* __restrict__ emb,
                                                   const unsigned char* __restrict__ ebB,
                                                   const float* __restrict__ en,
                                                   float* out, int M) {
    extern __shared__ char lds[];
    char* BsB = lds;                          // 65536 B swizzled bf16 chunk
    float* en_s = (float*)(lds + 65536);      // 128 floats

    const int t  = threadIdx.x;
    const int lane = t & 63;
    const int wv = t >> 6;                    // 0..15
    const int g  = lane >> 4;                 // 0..3
    const int lg = lane & 15;
    const long rbase = (long)blockIdx.x * 256 + wv * 16;

    const unsigned short* hb = (const unsigned short*)out;    // bf16 h rows
    const float* hnp = out + (size_t)M * ZD;                  // hn values

    short8 afrag[8];
    {
        const unsigned short* hr = hb + (rbase + lg) * 512;
        #pragma unroll
        for (int kt = 0; kt < 8; ++kt)
            afrag[kt] = *(const short8*)(hr + kt * 32 + g * 8);
    }
    float hnr[4], taur[4];
    #pragma unroll
    for (int i = 0; i < 4; ++i) {
        hnr[i] = hnp[rbase + g * 4 + i];
        // derived bound (see header comment): 2*Delta ~= 2.6e-4 worst-case
        taur[i] = 2.0e-6f * sqrtf(256.0f * hnr[i]) + 2.5e-4f;
    }

    const float INF = __builtin_inff();
    float bv0[4], bv1[4], bv2[4], bv3[4];
    int   bi0[4], bi1[4], bi2[4], bi3[4];
    #pragma unroll
    for (int i = 0; i < 4; ++i) {
        bv0[i] = INF; bv1[i] = INF; bv2[i] = INF; bv3[i] = INF;
        bi0[i] = 0;   bi1[i] = 0;   bi2[i] = 0;   bi3[i] = 0;
    }

    #pragma unroll 1
    for (int c = 0; c < 8; ++c) {
        { // stage pre-swizzled 64KB chunk linearly (coalesced, conflict-free)
            const uint4* src = (const uint4*)(ebB + (size_t)c * 65536);
            uint4* dst = (uint4*)BsB;
            #pragma unroll
            for (int p = 0; p < 4; ++p) dst[p * 1024 + t] = src[p * 1024 + t];
        }
        if (t < 32) {
            float4 v = *(const float4*)(en + c * 128 + t * 4);
            *(float4*)(en_s + t * 4) = v;
        }
        __syncthreads();

        #pragma unroll 1
        for (int nt = 0; nt < 8; ++nt) {
            f32x4 acc0 = {0.f, 0.f, 0.f, 0.f};
            f32x4 acc1 = {0.f, 0.f, 0.f, 0.f};
            const int nb = nt * 16 + lg;                       // entry in chunk
            const unsigned x = ((unsigned)lg & 7u) << 4;
            const unsigned rowb = (unsigned)nb * 512u;
            #pragma unroll
            for (int kt = 0; kt < 4; ++kt) {
                short8 b0 = *(const short8*)(BsB + ((rowb + (unsigned)kt * 64u + g * 16u) ^ x));
                short8 b1 = *(const short8*)(BsB + ((rowb + (unsigned)(kt + 4) * 64u + g * 16u) ^ x));
                acc0 = __builtin_amdgcn_mfma_f32_16x16x32_bf16(afrag[kt],     b0, acc0, 0, 0, 0);
                acc1 = __builtin_amdgcn_mfma_f32_16x16x32_bf16(afrag[kt + 4], b1, acc1, 0, 0, 0);
            }
            const int eIdx = c * 128 + nb;
            const float ene = en_s[nb];
            #pragma unroll
            for (int i = 0; i < 4; ++i) {
                float dot = __fadd_rn(acc0[i], acc1[i]);
                float d = __fsub_rn(__fadd_rn(hnr[i], ene), __fmul_rn(2.0f, dot));
                if (__any(d < bv3[i])) {
                    bool l3 = d < bv3[i], l2 = d < bv2[i], l1 = d < bv1[i], l0 = d < bv0[i];
                    bv3[i] = l3 ? (l2 ? bv2[i] : d) : bv3[i];
                    bi3[i] = l3 ? (l2 ? bi2[i] : eIdx) : bi3[i];
                    bv2[i] = l2 ? (l1 ? bv1[i] : d) : bv2[i];
                    bi2[i] = l2 ? (l1 ? bi1[i] : eIdx) : bi2[i];
                    bv1[i] = l1 ? (l0 ? bv0[i] : d) : bv1[i];
                    bi1[i] = l1 ? (l0 ? bi0[i] : eIdx) : bi1[i];
                    bv0[i] = l0 ? d : bv0[i];
                    bi0[i] = l0 ? eIdx : bi0[i];
                }
            }
        }
        __syncthreads();
    }

    float* out_q = out;
    float* out_i = out + (size_t)M * ZD;
    float* out_l = out_i + M;

    #pragma unroll 1
    for (int i = 0; i < 4; ++i) {
        const long r = rbase + g * 4 + i;

        float gmin = bv0[i];
        #pragma unroll
        for (int o = 1; o < 16; o <<= 1) gmin = fminf(gmin, __shfl_xor(gmin, o, 64));
        const float thr = gmin + taur[i];

        unsigned b0 = (unsigned)(__ballot(bv0[i] <= thr) >> (g * 16)) & 0xFFFFu;
        unsigned b1 = (unsigned)(__ballot(bv1[i] <= thr) >> (g * 16)) & 0xFFFFu;
        unsigned b2 = (unsigned)(__ballot(bv2[i] <= thr) >> (g * 16)) & 0xFFFFu;
        unsigned b3 = (unsigned)(__ballot(bv3[i] <= thr) >> (g * 16)) & 0xFFFFu;
        const int cnt = __popc(b0) + __popc(b1) + __popc(b2) + __popc(b3);
        const bool ex = (b3 != 0u) || (cnt > 7);

        if (cnt == 1 && !ex) {
            // single in-window candidate: provably the argmin; resolve now.
            if (bv0[i] <= thr) out_l[r] = (float)bi0[i];
        } else if (!ex) {
            float* rec = out_q + (size_t)r * ZD;
            if (lg == 0) {
                rec[0] = (float)cnt;
                out_l[r] = -(float)cnt;          // verify marker
            }
            const unsigned mlt = (1u << lg) - 1u;
            int base = 1;
            if (bv0[i] <= thr) rec[base + __popc(b0 & mlt)] = (float)bi0[i];
            base += __popc(b0);
            if (bv1[i] <= thr) rec[base + __popc(b1 & mlt)] = (float)bi1[i];
            base += __popc(b1);
            if (bv2[i] <= thr) rec[base + __popc(b2 & mlt)] = (float)bi2[i];
        } else {
            if (lg == 0) out_l[r] = -99.0f;      // exhaustive marker
        }
    }
}

// ---------------------------------------------------------------------------
// K2 merged finalize+stream (R16 verbatim — the proven-best form): 8192
// blocks x 256 thr, 16 rows/block (4/wave). Verify rows resolved with the
// wave-level body (coalesced 1KB stages into the wave's LDS slice, one
// bit-exact chain per lane, lex (d,idx) reduce), latency hidden under 32K
// waves of stream BW. Then R1's byte-exact epilogue.
// ---------------------------------------------------------------------------
__global__ __launch_bounds__(256) void vq_fs(const float* __restrict__ h,
                                             const float* __restrict__ emb,
                                             const float* __restrict__ en,
                                             float* __restrict__ out, int M) {
    extern __shared__ float Lall[];          // 4 waves x 8 rows x 260 floats
    const int t    = threadIdx.x;
    const int wv   = t >> 6;      // 0..3
    const int lane = t & 63;
    const int g    = lane >> 4;   // 0..3
    const int lg   = lane & 15;
    float* Lw = Lall + wv * (8 * 260);

    float* out_q = out;
    float* out_i = out + (size_t)M * ZD;
    float* out_l = out_i + M;
    const float INF = __builtin_inff();

    const long r = (long)blockIdx.x * 16 + wv * 4 + g;   // this group's row
    const float mk = out_l[r];                            // marker/besti
    int besti = (mk >= 0.f) ? (int)mk : 0;

    // ---- wave-level: resolve rows needing verification, one at a time ----
    unsigned long long vb = __ballot(mk < 0.f);
    #pragma unroll 1
    for (int gx = 0; gx < 4; ++gx) {
        if (!((vb >> (gx * 16)) & 1ull)) continue;
        const long rx = (long)blockIdx.x * 16 + wv * 4 + gx;
        const float mx = __shfl(mk, gx * 16, 64);
        const float hnx = out_i[rx];

        asm volatile("s_waitcnt lgkmcnt(0)" ::: "memory");  // WAR vs prev row

        int bix;
        if (mx > -50.f) {
            const int cnt = -(int)mx;                       // 2..7
            const float* rec = out_q + (size_t)rx * ZD;
            const float4 rA = *(const float4*)(rec);        // cnt,i0,i1,i2
            const float4 rB = *(const float4*)(rec + 4);    // i3,i4,i5,i6

            { // stage h row (coalesced 1KB, whole wave)
                float4 v = *(const float4*)(h + (size_t)rx * ZD + lane * 4);
                *(float4*)(Lw + lane * 4) = v;
            }
            #pragma unroll 1
            for (int q = 0; q < cnt; ++q) {   // stage candidate e rows
                const float fq = (q == 0) ? rA.y : (q == 1) ? rA.z : (q == 2) ? rA.w
                               : (q == 3) ? rB.x : (q == 4) ? rB.y : (q == 5) ? rB.z : rB.w;
                const int eidx = (int)fq;
                float4 v = *(const float4*)(emb + (size_t)eidx * ZD + lane * 4);
                *(float4*)(Lw + (1 + q) * 260 + lane * 4) = v;
            }
            asm volatile("s_waitcnt lgkmcnt(0)" ::: "memory");  // RAW

            float bd = INF;
            int   bi = 0x7FFFFFFF;
            if (lane < cnt) {
                const float fq = (lane == 0) ? rA.y : (lane == 1) ? rA.z : (lane == 2) ? rA.w
                               : (lane == 3) ? rB.x : (lane == 4) ? rB.y : (lane == 5) ? rB.z : rB.w;
                const int idx = (int)fq;
                const float* hl = Lw;
                const float* el = Lw + (1 + lane) * 260;
                float dot = 0.f;
                #pragma unroll 8
                for (int k = 0; k < ZD; k += 4) {
                    dot = fmaf(hl[k],     el[k],     dot);
                    dot = fmaf(hl[k + 1], el[k + 1], dot);
                    dot = fmaf(hl[k + 2], el[k + 2], dot);
                    dot = fmaf(hl[k + 3], el[k + 3], dot);
                }
                bd = __fsub_rn(__fadd_rn(hnx, en[idx]), __fmul_rn(2.0f, dot));
                bi = idx;
            }
            #pragma unroll
            for (int o = 1; o < 8; o <<= 1) {  // lex (d,idx) min, lanes 0..7
                float ov = __shfl_xor(bd, o, 8);
                int   oi = __shfl_xor(bi, o, 8);
                if (ov < bd || (ov == bd && oi < bi)) { bd = ov; bi = oi; }
            }
            bix = __shfl(bi, 0, 64);
        } else {
            // exhaustive (ultra-rare): h from LDS, lane-parallel over entries
            {
                float4 v = *(const float4*)(h + (size_t)rx * ZD + lane * 4);
                *(float4*)(Lw + lane * 4) = v;
            }
            asm volatile("s_waitcnt lgkmcnt(0)" ::: "memory");
            float bd = INF;
            int   bi = 0x7FFFFFFF;
            for (int e = lane; e < NE; e += 64) {
                const float* er = emb + (size_t)e * ZD;
                float dot = 0.f;
                #pragma unroll 8
                for (int k = 0; k < ZD; k += 4) {
                    float4 ev = *(const float4*)(er + k);
                    dot = fmaf(Lw[k],     ev.x, dot);
                    dot = fmaf(Lw[k + 1], ev.y, dot);
                    dot = fmaf(Lw[k + 2], ev.z, dot);
                    dot = fmaf(Lw[k + 3], ev.w, dot);
                }
                float dx = __fsub_rn(__fadd_rn(hnx, en[e]), __fmul_rn(2.0f, dot));
                if (dx < bd || (dx == bd && e < bi)) { bd = dx; bi = e; }
            }
            #pragma unroll
            for (int o = 1; o < 64; o <<= 1) {
                float ov = __shfl_xor(bd, o, 64);
                int   oi = __shfl_xor(bi, o, 64);
                if (ov < bd || (ov == bd && oi < bi)) { bd = ov; bi = oi; }
            }
            bix = __shfl(bi, 0, 64);
        }
        if (g == gx) besti = bix;
    }

    // ---- stream: R1's byte-exact epilogue for this group's row ----
    const float* hrow = h + (size_t)r * ZD;
    const float* erow = emb + (size_t)besti * ZD;
    float csum = 0.0f;
    #pragma unroll
    for (int q4 = 0; q4 < 4; ++q4) {
        int k = lg * 16 + q4 * 4;
        float4 hv = *(const float4*)(hrow + k);
        float4 ev = *(const float4*)(erow + k);
        float dx = __fsub_rn(ev.x, hv.x);
        float dy = __fsub_rn(ev.y, hv.y);
        float dz = __fsub_rn(ev.z, hv.z);
        float dw = __fsub_rn(ev.w, hv.w);
        float4 o;
        o.x = __fadd_rn(hv.x, dx);
        o.y = __fadd_rn(hv.y, dy);
        o.z = __fadd_rn(hv.z, dz);
        o.w = __fadd_rn(hv.w, dw);
        *(float4*)(out_q + (size_t)r * ZD + k) = o;
        csum = fmaf(dx, dx, csum);
        csum = fmaf(dy, dy, csum);
        csum = fmaf(dz, dz, csum);
        csum = fmaf(dw, dw, csum);
    }
    #pragma unroll
    for (int o2 = 1; o2 < 16; o2 <<= 1) csum += __shfl_xor(csum, o2, 64);
    if (lg == 0) {
        float cmean = csum * (1.0f / 256.0f);
        out_i[r] = (float)besti;
        out_l[r] = __fadd_rn(__fmul_rn(cmean, 0.1f), __fmul_rn(cmean, 0.2f));
    }
}

extern "C" void kernel_launch(void* const* d_in, const int* in_sizes, int n_in,
                              void* d_out, int out_size, void* d_ws, size_t ws_size,
                              hipStream_t stream) {
    const float* h   = (const float*)d_in[0];
    const float* emb = (const float*)d_in[1];
    const int M = in_sizes[0] / ZD;   // 131072

    unsigned char* ebB = (unsigned char*)d_ws;               // 512 KB bf16 swizzled
    float* en = (float*)(ebB + (size_t)NP * ZD * 2);         // 4 KB

    float* out = (float*)d_out;
    unsigned short* hb = (unsigned short*)d_out;             // bf16 h in out_q region
    float* hn = out + (size_t)M * ZD;                        // hn in out_i region

    prep_e<<<NP / 64, 64, 0, stream>>>(emb, ebB, en);
    prep_h<<<M / 64, 256, 0, stream>>>(h, hb, hn);

    const size_t lds_bytes = 65536 + 512;                    // 66 KB -> 2 blocks/CU
    (void)hipFuncSetAttribute((const void*)vq_main,
                              hipFuncAttributeMaxDynamicSharedMemorySize,
                              (int)lds_bytes);
    vq_main<<<M / 256, 1024, lds_bytes, stream>>>(h, emb, ebB, en, out, M);

    const size_t fs_lds = 4 * 8 * 260 * sizeof(float);       // 33280 B
    vq_fs<<<M / 16, 256, fs_lds, stream>>>(h, emb, en, out, M);
}